// Round 6
// baseline (44038.321 us; speedup 1.0000x reference)
//
#include <hip/hip_runtime.h>
#include <math.h>

#define NCHAR 256
#define NHID 2048
#define NSTACK 32
#define STACK 512
#define T 4096
#define NB 64           // persistent blocks
#define BT 1024         // 16 waves
#define RPB 32          // hid2hid rows per block (2 per wave)
#define HPP 2048        // h pairs per plane
#define PPP (64*128)    // P pairs per plane
#define TPP (32*8)      // tops pairs per plane (5 used, padded to 8)
#define AGENT __HIP_MEMORY_SCOPE_AGENT

// ---- self-validating {value,tag} record store: one 8B relaxed agent atomic ----
__device__ __forceinline__ void cohStoreRec(void* p, float v, float tag) {
  unsigned long long u = (unsigned long long)__float_as_uint(v) |
                         ((unsigned long long)__float_as_uint(tag) << 32);
  __hip_atomic_store((unsigned long long*)p, u, __ATOMIC_RELAXED, AGENT);
}
// ---- batched coherent loads (vector OUTPUTS are legal in gfx950 asm) ----
__device__ __forceinline__ void cohLoad2x16(const void* p, float4& r0, float4& r1) {
  asm volatile(
      "global_load_dwordx4 %0, %2, off sc0 sc1\n\t"
      "global_load_dwordx4 %1, %2, off offset:16 sc0 sc1\n\t"
      "s_waitcnt vmcnt(0)"
      : "=&v"(r0), "=&v"(r1) : "v"(p) : "memory");
}
__device__ __forceinline__ void cohLoad3x16(const void* p, float4& r0, float4& r1, float4& r2) {
  asm volatile(
      "global_load_dwordx4 %0, %3, off sc0 sc1\n\t"
      "global_load_dwordx4 %1, %3, off offset:16 sc0 sc1\n\t"
      "global_load_dwordx4 %2, %3, off offset:32 sc0 sc1\n\t"
      "s_waitcnt vmcnt(0)"
      : "=&v"(r0), "=&v"(r1), "=&v"(r2) : "v"(p) : "memory");
}
__device__ __forceinline__ void cohLoad8x16(const void* p,
    float4& a0, float4& a1, float4& a2, float4& a3,
    float4& a4, float4& a5, float4& a6, float4& a7) {
  asm volatile(
      "global_load_dwordx4 %0, %8, off sc0 sc1\n\t"
      "global_load_dwordx4 %1, %8, off offset:16 sc0 sc1\n\t"
      "global_load_dwordx4 %2, %8, off offset:1024 sc0 sc1\n\t"
      "global_load_dwordx4 %3, %8, off offset:1040 sc0 sc1\n\t"
      "global_load_dwordx4 %4, %8, off offset:2048 sc0 sc1\n\t"
      "global_load_dwordx4 %5, %8, off offset:2064 sc0 sc1\n\t"
      "global_load_dwordx4 %6, %8, off offset:3072 sc0 sc1\n\t"
      "global_load_dwordx4 %7, %8, off offset:3088 sc0 sc1\n\t"
      "s_waitcnt vmcnt(0)"
      : "=&v"(a0), "=&v"(a1), "=&v"(a2), "=&v"(a3),
        "=&v"(a4), "=&v"(a5), "=&v"(a6), "=&v"(a7)
      : "v"(p) : "memory");
}

__global__ __launch_bounds__(BT, 4)
__attribute__((amdgpu_waves_per_eu(4, 4)))
void stackrnn_seq(
    const int* __restrict__ tokens,
    const float* __restrict__ in2hid,    // [NHID][NCHAR]
    const float* __restrict__ hid2hid,   // [NHID][NHID]
    const float* __restrict__ hid2act,   // [NSTACK][3][NHID]
    const float* __restrict__ hid2stack, // [NSTACK][STACK][NHID]
    const float* __restrict__ stack2hid, // [NSTACK][NHID][STACK]
    const float* __restrict__ hid2out,   // [NCHAR][NHID]
    float* __restrict__ out,             // [T][NCHAR] logits (softmax later)
    float2* __restrict__ HP,             // [3][HPP] {h,tag}
    float2* __restrict__ PP,             // [3][PPP] {p,tag} quad-permuted [blk][128]
    float2* __restrict__ TP)             // [3][TPP] {top,tag}
{
  __shared__ int    sTok[T];             // 16 KB
  __shared__ float4 sH[576];             // h_{w-1}, float4 idx i -> i+(i>>3)
  __shared__ float4 sPq[32][17];         // stage-1 P partials (padded)
  __shared__ float  sLl[16][128];        // per-wave logit partials
  __shared__ float  sSt[2][STACK];       // owner stack neighbor exchange
  __shared__ float  sActs[NSTACK][3];
  __shared__ float  sTopv[NSTACK];
  __shared__ float  sTops[NSTACK][4];
  __shared__ float  sOut[16];

  const int tid = threadIdx.x;
  const int b   = blockIdx.x;
  const int wv  = tid >> 6;
  const int l   = tid & 63;
  const int r0  = b * RPB + 2 * wv;
  const int r1  = r0 + 1;

  // ---- register-resident hid2hid rows (2 rows x 32 cols per lane) ----
  float wA[32], wB[32];
  {
    const float4* pa = (const float4*)(hid2hid + (size_t)r0 * NHID + 32 * l);
    const float4* pb = (const float4*)(hid2hid + (size_t)r1 * NHID + 32 * l);
#pragma unroll
    for (int j = 0; j < 8; ++j) {
      float4 v = pa[j];
      wA[4*j] = v.x; wA[4*j+1] = v.y; wA[4*j+2] = v.z; wA[4*j+3] = v.w;
    }
#pragma unroll
    for (int j = 0; j < 8; ++j) {
      float4 v = pb[j];
      wB[4*j] = v.x; wB[4*j+1] = v.y; wB[4*j+2] = v.z; wB[4*j+3] = v.w;
    }
  }
  // ---- P weights, quad-permuted: logit g=4s+k -> (k<3 ? act row 3s+k : topv s) ----
  float wl00, wl01, wl10, wl11;
  {
    const int g0 = 2 * l, g1 = 2 * l + 1;
    const int s0 = g0 >> 2, k0 = g0 & 3, s1 = g1 >> 2, k1 = g1 & 3;
    const float* p0 = (k0 < 3) ? (hid2act + (size_t)(3 * s0 + k0) * NHID)
                               : (hid2stack + (size_t)s0 * STACK * NHID);
    const float* p1 = (k1 < 3) ? (hid2act + (size_t)(3 * s1 + k1) * NHID)
                               : (hid2stack + (size_t)s1 * STACK * NHID);
    wl00 = p0[r0]; wl01 = p0[r1];
    wl10 = p1[r0]; wl11 = p1[r1];
  }
  // ---- stack2hid slice: lane covers stack cs, depths cd,cd+1 ----
  const int cs = l >> 1, cd = (l & 1) * 2;
  float w2a0, w2a1, w2b0, w2b1;
  {
    const float* p = stack2hid + (size_t)cs * NHID * STACK;
    w2a0 = p[(size_t)r0 * STACK + cd]; w2a1 = p[(size_t)r0 * STACK + cd + 1];
    w2b0 = p[(size_t)r1 * STACK + cd]; w2b1 = p[(size_t)r1 * STACK + cd + 1];
  }
  // ---- output-column weights: wave wv -> col 4b+(wv&3), quarter oseg ----
  const int oseg = wv >> 2;
  float wo[8];
  {
    const int ocol = 4 * b + (wv & 3);
    const float4* p = (const float4*)(hid2out + (size_t)ocol * NHID + oseg * 512 + 8 * l);
    float4 v0 = p[0], v1 = p[1];
    wo[0] = v0.x; wo[1] = v0.y; wo[2] = v0.z; wo[3] = v0.w;
    wo[4] = v1.x; wo[5] = v1.y; wo[6] = v1.z; wo[7] = v1.w;
  }

  for (int i = tid; i < T; i += BT) sTok[i] = tokens[i];
  float bval = -1.f;   // owner-stack element (blocks 0..31, threads 512.., depth tid-512)

  __syncthreads();

#pragma unroll 1
  for (int w = 0; w < T; ++w) {
    const int plc = (w + 2) % 3;       // consume plane (w-1)%3
    const int plp = w % 3;             // produce plane
    const float tgc = (float)w;
    const float tgp = (float)(w + 1);
    const int xt = sTok[w];
    const float e0 = in2hid[(size_t)r0 * NCHAR + xt];
    const float e1 = in2hid[(size_t)r1 * NCHAR + xt];

    // ---- spin-consume step w-1 publishes (self-validating tags) ----
    float tg0 = -1.f, tg1 = -1.f, tg2 = -1.f, tg3 = -1.f, tg4 = -1.f;
    if (w > 0) {
      if (tid < 512) {
        const float2* hp = HP + (size_t)plc * HPP + 4 * tid;
        float4 x0, x1;
        do { cohLoad2x16(hp, x0, x1); }
        while (x0.y != tgc || x0.w != tgc || x1.y != tgc || x1.w != tgc);
        sH[tid + (tid >> 3)] = make_float4(x0.x, x0.z, x1.x, x1.z);
        if (tid < NSTACK) {
          const float2* tp = TP + (size_t)plc * TPP + 8 * tid;
          float4 t0, t1, t2;
          do { cohLoad3x16(tp, t0, t1, t2); }
          while (t0.y != tgc || t0.w != tgc || t1.y != tgc || t1.w != tgc || t2.y != tgc);
          tg0 = t0.x; tg1 = t0.z; tg2 = t1.x; tg3 = t1.z; tg4 = t2.x;
        }
      } else {
        const int v = tid - 512, q = v >> 4, bg = v & 15;
        const float2* pp = PP + (size_t)plc * PPP + (size_t)(4 * bg) * 128 + 4 * q;
        float4 a0, a1, a2, a3, a4, a5, a6, a7;
        do { cohLoad8x16(pp, a0, a1, a2, a3, a4, a5, a6, a7); }
        while (a0.y != tgc || a0.w != tgc || a1.y != tgc || a1.w != tgc ||
               a2.y != tgc || a2.w != tgc || a3.y != tgc || a3.w != tgc ||
               a4.y != tgc || a4.w != tgc || a5.y != tgc || a5.w != tgc ||
               a6.y != tgc || a6.w != tgc || a7.y != tgc || a7.w != tgc);
        float4 s4;
        s4.x = a0.x + a2.x + a4.x + a6.x;
        s4.y = a0.z + a2.z + a4.z + a6.z;
        s4.z = a1.x + a3.x + a5.x + a7.x;
        s4.w = a1.z + a3.z + a5.z + a7.z;
        sPq[q][bg] = s4;
      }
    }
    __syncthreads();  // B1: sH / sPq ready

    // ---- acts/topv/blended tops (tid<32) | matvec main + out-dot (all) ----
    if (tid < NSTACK) {
      if (w > 0) {
        float4 a = make_float4(0.f, 0.f, 0.f, 0.f);
#pragma unroll
        for (int g = 0; g < 16; ++g) {
          const float4 p = sPq[tid][(g + tid) & 15];
          a.x += p.x; a.y += p.y; a.z += p.z; a.w += p.w;
        }
        const float m  = fmaxf(a.x, fmaxf(a.y, a.z));
        const float ea = expf(a.x - m), eb = expf(a.y - m), ec = expf(a.z - m);
        const float inv = 1.f / (ea + eb + ec);
        const float qw = ea * inv, pwt = eb * inv, nw = ec * inv;  // pop,push,noop
        sActs[tid][0] = qw; sActs[tid][1] = pwt; sActs[tid][2] = nw;
        float tv = fminf(50.f, fmaxf(-50.f, a.w));
        tv = 1.f / (1.f + expf(-tv));
        sTopv[tid] = tv;
        sTops[tid][0] = pwt * tv  + qw * tg1 + nw * tg0;
        sTops[tid][1] = pwt * tg0 + qw * tg2 + nw * tg1;
        sTops[tid][2] = pwt * tg1 + qw * tg3 + nw * tg2;
        sTops[tid][3] = pwt * tg2 + qw * tg4 + nw * tg3;
      } else {
        sActs[tid][0] = sActs[tid][1] = sActs[tid][2] = 0.f;
        sTopv[tid] = 0.f;
        sTops[tid][0] = sTops[tid][1] = sTops[tid][2] = sTops[tid][3] = -1.f;
      }
    }
    float acc0 = 0.f, acc1 = 0.f;
    if (w > 0) {
#pragma unroll
      for (int j = 0; j < 8; ++j) {
        const float4 hv = sH[9 * l + j];
        acc0 += wA[4*j]*hv.x + wA[4*j+1]*hv.y + wA[4*j+2]*hv.z + wA[4*j+3]*hv.w;
        acc1 += wB[4*j]*hv.x + wB[4*j+1]*hv.y + wB[4*j+2]*hv.z + wB[4*j+3]*hv.w;
      }
      // deferred output columns of h_{w-1} (reads sH only)
      const int f0 = oseg * 128 + 2 * l;
      const float4 hv0 = sH[f0 + (f0 >> 3)];
      const float4 hv1 = sH[(f0 + 1) + ((f0 + 1) >> 3)];
      float dv = wo[0]*hv0.x + wo[1]*hv0.y + wo[2]*hv0.z + wo[3]*hv0.w
               + wo[4]*hv1.x + wo[5]*hv1.y + wo[6]*hv1.z + wo[7]*hv1.w;
#pragma unroll
      for (int m = 1; m < 64; m <<= 1) dv += __shfl_xor(dv, m);
      if (l == 0) sOut[wv] = dv;
    }
    __syncthreads();  // B2: sTops/sActs ready; all sH reads done

    // ---- finish matvec -> h rows -> publish immediately ----
    acc0 += w2a0 * sTops[cs][cd] + w2a1 * sTops[cs][cd + 1];
    acc1 += w2b0 * sTops[cs][cd] + w2b1 * sTops[cs][cd + 1];
#pragma unroll
    for (int m = 1; m < 64; m <<= 1) {
      acc0 += __shfl_xor(acc0, m);
      acc1 += __shfl_xor(acc1, m);
    }
    const float h0 = 1.f / (1.f + expf(-(acc0 + e0)));
    const float h1 = 1.f / (1.f + expf(-(acc1 + e1)));
    if (l == 0) {
      cohStoreRec(HP + (size_t)plp * HPP + r0, h0, tgp);
      cohStoreRec(HP + (size_t)plp * HPP + r1, h1, tgp);
    }
    *(float2*)&sLl[wv][2 * l] =
        make_float2(wl00 * h0 + wl01 * h1, wl10 * h0 + wl11 * h1);

    // ---- owner stack blend (blocks 0..31, threads 512..1023) ----
    if (b < NSTACK && tid >= 512) {
      const int d = tid - 512;
      const int pw_ = w & 1, pr_ = pw_ ^ 1;
      float nv;
      if (w > 0) {
        const float left   = (d > 0) ? sSt[pr_][d - 1] : 0.f;
        const float pushed = (d == 0) ? sTopv[b] : left;
        const float popped = (d < STACK - 1) ? sSt[pr_][d + 1] : -1.f;
        nv = sActs[b][1] * pushed + sActs[b][0] * popped + sActs[b][2] * bval;
      } else {
        nv = -1.f;
      }
      bval = nv;
      sSt[pw_][d] = nv;
      if (d < 5)
        cohStoreRec(TP + (size_t)plp * TPP + 8 * b + d, nv, tgp);
    }
    // ---- out[w-1] finalize ----
    if (w > 0 && tid < 4)
      out[(size_t)(w - 1) * NCHAR + 4 * b + tid] =
          sOut[tid] + sOut[4 + tid] + sOut[8 + tid] + sOut[12 + tid];
    __syncthreads();  // B3: sLl complete

    // ---- P publish ----
    if (tid < 128) {
      float pv = 0.f;
#pragma unroll
      for (int g = 0; g < 16; ++g) pv += sLl[g][tid];
      cohStoreRec(PP + (size_t)plp * PPP + (size_t)b * 128 + tid, pv, tgp);
    }
  }

  // ---- tail: output columns of h_{T-1} ----
  {
    const int plc = (T - 1) % 3;
    const float tgc = (float)T;
    if (tid < 512) {
      const float2* hp = HP + (size_t)plc * HPP + 4 * tid;
      float4 x0, x1;
      do { cohLoad2x16(hp, x0, x1); }
      while (x0.y != tgc || x0.w != tgc || x1.y != tgc || x1.w != tgc);
      sH[tid + (tid >> 3)] = make_float4(x0.x, x0.z, x1.x, x1.z);
    }
    __syncthreads();
    const int f0 = oseg * 128 + 2 * l;
    const float4 hv0 = sH[f0 + (f0 >> 3)];
    const float4 hv1 = sH[(f0 + 1) + ((f0 + 1) >> 3)];
    float dv = wo[0]*hv0.x + wo[1]*hv0.y + wo[2]*hv0.z + wo[3]*hv0.w
             + wo[4]*hv1.x + wo[5]*hv1.y + wo[6]*hv1.z + wo[7]*hv1.w;
#pragma unroll
    for (int m = 1; m < 64; m <<= 1) dv += __shfl_xor(dv, m);
    if (l == 0) sOut[wv] = dv;
    __syncthreads();
    if (tid < 4)
      out[(size_t)(T - 1) * NCHAR + 4 * b + tid] =
          sOut[tid] + sOut[4 + tid] + sOut[8 + tid] + sOut[12 + tid];
  }
}

// ---------------- row softmax over NCHAR=256 ----------------
__global__ __launch_bounds__(64) void row_softmax(float* __restrict__ out) {
  const int t = blockIdx.x;
  const int l = threadIdx.x;
  float4* p = (float4*)(out + (size_t)t * NCHAR);
  float4 v = p[l];
  float m = fmaxf(fmaxf(v.x, v.y), fmaxf(v.z, v.w));
#pragma unroll
  for (int k = 1; k < 64; k <<= 1) m = fmaxf(m, __shfl_xor(m, k));
  const float ex = expf(v.x - m), ey = expf(v.y - m);
  const float ez = expf(v.z - m), ew = expf(v.w - m);
  float s = ex + ey + ez + ew;
#pragma unroll
  for (int k = 1; k < 64; k <<= 1) s += __shfl_xor(s, k);
  const float inv = 1.f / s;
  p[l] = make_float4(ex * inv, ey * inv, ez * inv, ew * inv);
}

extern "C" void kernel_launch(void* const* d_in, const int* in_sizes, int n_in,
                              void* d_out, int out_size, void* d_ws, size_t ws_size,
                              hipStream_t stream) {
  const int*   tokens    = (const int*)d_in[0];
  const float* in2hid    = (const float*)d_in[1];
  const float* hid2hid   = (const float*)d_in[2];
  const float* hid2act   = (const float*)d_in[3];
  const float* hid2stack = (const float*)d_in[4];
  const float* stack2hid = (const float*)d_in[5];
  const float* hid2out   = (const float*)d_in[6];
  float* out = (float*)d_out;

  float2* HP = (float2*)d_ws;            // 3*HPP pairs
  float2* PP = HP + 3 * HPP;             // 3*PPP pairs
  float2* TP = PP + 3 * PPP;             // 3*TPP pairs

  hipLaunchKernelGGL(stackrnn_seq, dim3(NB), dim3(BT), 0, stream,
                     tokens, in2hid, hid2hid, hid2act, hid2stack, stack2hid,
                     hid2out, out, HP, PP, TP);
  hipLaunchKernelGGL(row_softmax, dim3(T), dim3(64), 0, stream, out);
}